// Round 12
// baseline (316.730 us; speedup 1.0000x reference)
//
#include <hip/hip_runtime.h>

typedef short s16x8 __attribute__((ext_vector_type(8)));
typedef float f32x4 __attribute__((ext_vector_type(4)));

__device__ __forceinline__ unsigned short f2bf(float f) {
    union { float f; unsigned u; } v; v.f = f;
    return (unsigned short)((v.u + 0x7FFFu + ((v.u >> 16) & 1u)) >> 16);
}
__device__ __forceinline__ float bf2f(unsigned short h) {
    union { unsigned u; float f; } v; v.u = ((unsigned)h) << 16;
    return v.f;
}

// LDS-only barrier: does NOT drain vmcnt, so register prefetch loads stay in
// flight across it. sched_barrier(0) fences compiler motion (rule #18).
__device__ __forceinline__ void wg_barrier_lds() {
    __builtin_amdgcn_sched_barrier(0);
    asm volatile("s_waitcnt lgkmcnt(0)" ::: "memory");
    __builtin_amdgcn_s_barrier();
    __builtin_amdgcn_sched_barrier(0);
}

#define NBLK 1024   // 16384 positions / 16 per block

// ---------- prep: W1 (512x256 f32) -> W1T bf16 [16][256][32]; Wf -> WfT bf16 [8][256][32] ----------
__global__ void prep_weights(const float* __restrict__ W1, const float* __restrict__ Wf,
                             unsigned short* __restrict__ W1T, unsigned short* __restrict__ WfT) {
    int t = blockIdx.x * 256 + threadIdx.x;      // 131072 threads
    {   // W1T[t]: t = ((c*256)+n)*32 + kk
        int c  = t >> 13;
        int n  = (t >> 5) & 255;
        int kk = t & 31;
        W1T[t] = f2bf(W1[(c * 32 + kk) * 256 + n]);
    }
    if (t < 65536) {
        int c  = t >> 13;
        int n  = (t >> 5) & 255;
        int hh = t & 31;
        WfT[t] = f2bf(Wf[(c * 32 + hh) * 257 + n]);
    }
}

// Row-streaming design: iteration p = one position = 16 full net_in rows read
// SEQUENTIALLY (32KB contiguous per block per iteration -> DRAM-friendly).
// 1024 threads = 16 waves = 4 waves/SIMD; LDS 93.5KB -> 1 block/CU (envelope).
__global__ __launch_bounds__(1024)
void fused_embed(const float* __restrict__ net_in, const float* __restrict__ embeds,
                 const float* __restrict__ mg, const float* __restrict__ W1,
                 const float* __restrict__ b1, const float* __restrict__ Wf,
                 const float* __restrict__ bfv, const float* __restrict__ gam,
                 const float* __restrict__ bet, float* __restrict__ out,
                 const unsigned short* __restrict__ W1T, const unsigned short* __restrict__ WfT)
{
    // LDS: 65536 + 2560 + 8448 + 16896 + 64 = 93504 B -> 1 block/CU
    __shared__ unsigned short Abuf[4][16][512];   // 4-deep ring, XOR-swizzled rows
    __shared__ float lcpart[2][16][20];           // link-col partials [parity][k][wave]
    __shared__ unsigned short gbuf[16][264];      // g rows: 16 positions
    __shared__ float updb[16][264];               // updates (16 positions x 256), f32
    __shared__ float sbuf[16];                    // s_p = sum_k w_k m_k

    const int tid  = threadIdx.x;
    const int lane = tid & 63;
    const int wid  = tid >> 6;     // 0..15
    const int l15  = lane & 15;
    const int g8   = (lane >> 4) * 8;
    const int q4   = (lane >> 4) * 4;
    const int blk  = blockIdx.x;
    const int row0 = blk * 256;

    const f32x4 zero4 = {0.f, 0.f, 0.f, 0.f};

    // resident W1 fragments: wave wid owns output cols [wid*16, +16), all K
    s16x8 wfrag[16];
    #pragma unroll
    for (int kk = 0; kk < 16; ++kk)
        wfrag[kk] = *(const s16x8*)(W1T + kk * 8192 + (wid * 16 + l15) * 32 + g8);

    const float wlv   = Wf[(wid * 16 + l15) * 257 + 256];   // link weight for my col
    const float bbv   = b1[wid * 16 + l15];                 // bias for my col
    const float bf256 = bfv[256];

    // sequential A segment: iteration p reads floats [p*8192 + tid*8, +8)
    const float* aseg = net_in + (size_t)row0 * 512 + tid * 8;
    // swizzled LDS write address (wave wid writes row wid, 1KB contiguous)
    unsigned short* awr = &Abuf[0][0][0] + wid * 512 + (((lane * 16) ^ ((wid & 7) << 4)) >> 1);

    float4 va[2], vb[2];
#define A_ISSUE(P, S) do { \
        va[S] = *(const float4*)(aseg + (P) * 8192); \
        vb[S] = *(const float4*)(aseg + (P) * 8192 + 4); \
    } while (0)
#define A_WRITE(P, S) do { \
        int4 _pk; \
        asm("v_cvt_pk_bf16_f32 %0, %1, %2" : "=v"(_pk.x) : "v"(va[S].x), "v"(va[S].y)); \
        asm("v_cvt_pk_bf16_f32 %0, %1, %2" : "=v"(_pk.y) : "v"(va[S].z), "v"(va[S].w)); \
        asm("v_cvt_pk_bf16_f32 %0, %1, %2" : "=v"(_pk.z) : "v"(vb[S].x), "v"(vb[S].y)); \
        asm("v_cvt_pk_bf16_f32 %0, %1, %2" : "=v"(_pk.w) : "v"(vb[S].z), "v"(vb[S].w)); \
        *(int4*)(awr + ((P) & 3) * 8192) = _pk; \
    } while (0)

    float u256 = 0.f;

    // prologue: segments 0,1 in flight; 0 written
    A_ISSUE(0, 0);
    A_ISSUE(1, 1);
    A_WRITE(0, 0);
    wg_barrier_lds();

    #pragma unroll
    for (int p = 0; p < 16; ++p) {
        // issue segment p+2 into the reg slot freed last iteration
        if (p < 14) A_ISSUE(p + 2, p & 1);
        // write segment p+1 (its loads got a full iteration of cover)
        if (p < 15) A_WRITE(p + 1, (p + 1) & 1);

        // ===== MFMA: 16x16 tile for position p (rows=k 0..15, cols=wid slice) =====
        f32x4 acc = zero4;
        const unsigned short* arow = &Abuf[p & 3][l15][0];
        #pragma unroll
        for (int kk = 0; kk < 16; ++kk) {
            s16x8 af = *(const s16x8*)(arow + (((kk * 64 + (lane >> 4) * 16) ^ ((l15 & 7) << 4)) >> 1));
            acc = __builtin_amdgcn_mfma_f32_16x16x32_bf16(af, wfrag[kk], acc, 0, 0, 0);
        }

        // ===== H = relu(acc+b1), rounded to bf16 (matches validated numerics) =====
        float h0 = bf2f(f2bf(fmaxf(acc[0] + bbv, 0.f)));
        float h1 = bf2f(f2bf(fmaxf(acc[1] + bbv, 0.f)));
        float h2 = bf2f(f2bf(fmaxf(acc[2] + bbv, 0.f)));
        float h3 = bf2f(f2bf(fmaxf(acc[3] + bbv, 0.f)));

        // ===== link-col partials over my 16 cols -> lcpart[parity][k][wid] =====
        float p0 = h0 * wlv, p1 = h1 * wlv, p2 = h2 * wlv, p3 = h3 * wlv;
        #pragma unroll
        for (int off = 1; off < 16; off <<= 1) {
            p0 += __shfl_xor(p0, off, 64);
            p1 += __shfl_xor(p1, off, 64);
            p2 += __shfl_xor(p2, off, 64);
            p3 += __shfl_xor(p3, off, 64);
        }
        if (l15 == 0) {
            lcpart[p & 1][q4 + 0][wid] = p0;
            lcpart[p & 1][q4 + 1][wid] = p1;
            lcpart[p & 1][q4 + 2][wid] = p2;
            lcpart[p & 1][q4 + 3][wid] = p3;
        }

        wg_barrier_lds();   // publishes: A(p+1) staging + lcpart(p) partials

        // ===== softmax weights (computed redundantly by every wave) =====
        float uu = 0.f, wwreg = 0.f;
        if (lane < 16) {
            const float* lrow = &lcpart[p & 1][lane][0];
            float4 la = *(const float4*)(lrow);
            float4 lb = *(const float4*)(lrow + 4);
            float4 lc = *(const float4*)(lrow + 8);
            float4 ld = *(const float4*)(lrow + 12);
            float lcs = la.x + la.y + la.z + la.w + lb.x + lb.y + lb.z + lb.w
                      + lc.x + lc.y + lc.z + lc.w + ld.x + ld.y + ld.z + ld.w;
            float raw = lcs + bf256;
            float mv  = mg[(blk * 16 + p) * 16 + lane];
            float sg  = 1.f / (1.f + expf(-raw));
            float v   = mv * sg;
            float lw  = v + 1e-8f;
            float nrm = lw;
            #pragma unroll
            for (int off = 8; off > 0; off >>= 1) nrm += __shfl_xor(nrm, off, 16);
            float wk = lw / nrm;
            wwreg = wk * mv;
            float u = wk * v;
            float s = wwreg;
            #pragma unroll
            for (int off = 8; off > 0; off >>= 1) {
                u += __shfl_xor(u, off, 16);
                s += __shfl_xor(s, off, 16);
            }
            uu = u;
            if (wid == p && lane == 0) sbuf[p] = s;
        }
        float ub = __shfl(uu, 0, 64);
        if (wid == p) u256 = ub;

        // ===== g slice: g[col] = sum_k ww_k h_k[col] -> gbuf[p] =====
        float w0 = __shfl(wwreg, q4 + 0, 64);
        float w1 = __shfl(wwreg, q4 + 1, 64);
        float w2 = __shfl(wwreg, q4 + 2, 64);
        float w3 = __shfl(wwreg, q4 + 3, 64);
        float gp = h0 * w0 + h1 * w1 + h2 * w2 + h3 * w3;
        gp += __shfl_xor(gp, 16, 64);
        gp += __shfl_xor(gp, 32, 64);
        if (lane < 16) gbuf[p][wid * 16 + l15] = f2bf(gp);
    }
#undef A_ISSUE
#undef A_WRITE

    __syncthreads();   // gbuf all 16 rows + sbuf visible

    // ========== GEMM2': updates = g @ Wf[:, :256] — B from L2, ZERO barriers ==========
    f32x4 acc2 = zero4;
    {
        const int n0 = (wid * 16 + l15) * 32 + g8;
        s16x8 w2[2];
        w2[0] = *(const s16x8*)(WfT + n0);
        #pragma unroll
        for (int c2 = 0; c2 < 8; ++c2) {
            const int cur = c2 & 1;
            s16x8 bw = w2[cur];
            if (c2 < 7) w2[cur ^ 1] = *(const s16x8*)(WfT + (c2 + 1) * 8192 + n0);
            s16x8 ga = *(const s16x8*)&gbuf[l15][c2 * 32 + g8];
            acc2 = __builtin_amdgcn_mfma_f32_16x16x32_bf16(ga, bw, acc2, 0, 0, 0);
        }
    }

    // updates -> LDS (all 16 D-rows are real positions)
    {
        int col = wid * 16 + l15;
        float bfc = bfv[col];
        #pragma unroll
        for (int r = 0; r < 4; ++r) {
            int pp = q4 + r;
            updb[pp][col] = acc2[r] + sbuf[pp] * bfc;
        }
    }
    __syncthreads();

    // ========== embeds update + LayerNorm (wave wid owns position wid) ==========
    {
        int base = (blk * 16 + wid) * 256;
        float4 up = *(const float4*)&updb[wid][lane * 4];
        float4 em = *(const float4*)&embeds[base + lane * 4];
        float e0 = em.x + u256 * up.x;
        float e1 = em.y + u256 * up.y;
        float e2 = em.z + u256 * up.z;
        float e3 = em.w + u256 * up.w;
        float s1 = e0 + e1 + e2 + e3;
        float s2 = e0 * e0 + e1 * e1 + e2 * e2 + e3 * e3;
        #pragma unroll
        for (int off = 32; off > 0; off >>= 1) {
            s1 += __shfl_xor(s1, off, 64);
            s2 += __shfl_xor(s2, off, 64);
        }
        float mu  = s1 * (1.f / 256.f);
        float var = s2 * (1.f / 256.f) - mu * mu;
        float rs  = rsqrtf(var + 1e-5f);
        float4 gm = *(const float4*)&gam[lane * 4];
        float4 bt = *(const float4*)&bet[lane * 4];
        float4 o;
        o.x = (e0 - mu) * rs * gm.x + bt.x;
        o.y = (e1 - mu) * rs * gm.y + bt.y;
        o.z = (e2 - mu) * rs * gm.z + bt.z;
        o.w = (e3 - mu) * rs * gm.w + bt.w;
        *(float4*)&out[base + lane * 4] = o;
    }
}

extern "C" void kernel_launch(void* const* d_in, const int* in_sizes, int n_in,
                              void* d_out, int out_size, void* d_ws, size_t ws_size,
                              hipStream_t stream) {
    (void)in_sizes; (void)n_in; (void)ws_size; (void)out_size;
    const float* net_in = (const float*)d_in[0];
    const float* embeds = (const float*)d_in[1];
    const float* mg     = (const float*)d_in[2];
    const float* W1     = (const float*)d_in[3];
    const float* b1     = (const float*)d_in[4];
    const float* Wf     = (const float*)d_in[5];
    const float* bfv    = (const float*)d_in[6];
    const float* gam    = (const float*)d_in[7];
    const float* bet    = (const float*)d_in[8];
    float* outp = (float*)d_out;

    unsigned short* W1T = (unsigned short*)d_ws;                 // 16*256*32 = 131072 elems
    unsigned short* WfT = W1T + 131072;                          //  8*256*32 =  65536 elems

    prep_weights<<<512, 256, 0, stream>>>(W1, Wf, W1T, WfT);
    fused_embed<<<NBLK, 1024, 0, stream>>>(net_in, embeds, mg, W1, b1, Wf, bfv, gam, bet, outp, W1T, WfT);
}

// Round 13
// 215.799 us; speedup vs baseline: 1.4677x; 1.4677x over previous
//
#include <hip/hip_runtime.h>

typedef short s16x8 __attribute__((ext_vector_type(8)));
typedef float f32x4 __attribute__((ext_vector_type(4)));

__device__ __forceinline__ unsigned short f2bf(float f) {
    union { float f; unsigned u; } v; v.f = f;
    return (unsigned short)((v.u + 0x7FFFu + ((v.u >> 16) & 1u)) >> 16);
}
__device__ __forceinline__ float bf2f(unsigned short h) {
    union { unsigned u; float f; } v; v.u = ((unsigned)h) << 16;
    return v.f;
}

// LDS-only barrier: does NOT drain vmcnt, so register prefetch loads stay in
// flight across it. sched_barrier(0) fences compiler motion (rule #18).
__device__ __forceinline__ void wg_barrier_lds() {
    __builtin_amdgcn_sched_barrier(0);
    asm volatile("s_waitcnt lgkmcnt(0)" ::: "memory");
    __builtin_amdgcn_s_barrier();
    __builtin_amdgcn_sched_barrier(0);
}

#define NBLK 2048   // 16384 positions / 8 per block

// ---------- prep: W1 (512x256 f32) -> W1T bf16 [16][256][32]; Wf -> WfT bf16 [8][256][32] ----------
__global__ void prep_weights(const float* __restrict__ W1, const float* __restrict__ Wf,
                             unsigned short* __restrict__ W1T, unsigned short* __restrict__ WfT) {
    int t = blockIdx.x * 256 + threadIdx.x;      // 131072 threads
    {   // W1T[t]: t = ((c*256)+n)*32 + kk
        int c  = t >> 13;
        int n  = (t >> 5) & 255;
        int kk = t & 31;
        W1T[t] = f2bf(W1[(c * 32 + kk) * 256 + n]);
    }
    if (t < 65536) {
        int c  = t >> 13;
        int n  = (t >> 5) & 255;
        int hh = t & 31;
        WfT[t] = f2bf(Wf[(c * 32 + hh) * 257 + n]);
    }
}

// R8 structure + BK=64: 8 K-iterations, 256B-contiguous per net_in row per
// iteration (2x DRAM page-hits), half the barrier drains. 512 threads, 1
// block/CU by LDS (validated envelope; multi-block failed 5/5).
__global__ __launch_bounds__(512, 2)
void fused_embed(const float* __restrict__ net_in, const float* __restrict__ embeds,
                 const float* __restrict__ mg, const float* __restrict__ W1,
                 const float* __restrict__ b1, const float* __restrict__ Wf,
                 const float* __restrict__ bfv, const float* __restrict__ gam,
                 const float* __restrict__ bet, float* __restrict__ out,
                 const unsigned short* __restrict__ W1T, const unsigned short* __restrict__ WfT)
{
    // LDS: 36864 + 66560 + 8448 + 8448 + 32 = 120352 B -> 1 block/CU
    __shared__ unsigned short Abuf[2][128][72];   // BK=64 chunk, +8 shorts pad (8/bank min on write & read)
    __shared__ unsigned short Hbuf[128][260];     // H = relu(A@W1+b1), bf16 (520B rows)
    __shared__ unsigned short gbuf[16][264];      // g rows (8 used + 8 zero pad), bf16
    __shared__ float updb[8][264];                // updates (positions x 256), f32
    __shared__ float sbuf[8];                     // s_p = sum_k w_k m_k

    const int tid  = threadIdx.x;
    const int lane = tid & 63;
    const int wid  = tid >> 6;     // 0..7
    const int wr   = wid >> 2;     // 0..1 (row group: 64 rows)
    const int wc   = wid & 3;      // 0..3 (col group: 64 cols)
    const int l15  = lane & 15;
    const int g8   = (lane >> 4) * 8;
    const int blk  = blockIdx.x;
    const int row0 = blk * 128;

    const f32x4 zero4 = {0.f, 0.f, 0.f, 0.f};

    // ================= GEMM1: H = relu(net_in @ W1 + b1), BK=64 =================
    f32x4 acc[4][4];
    #pragma unroll
    for (int i = 0; i < 4; ++i)
        #pragma unroll
        for (int j = 0; j < 4; ++j)
            acc[i][j] = zero4;

    const int ar = tid >> 2;           // A-staging row this thread owns (0..127)
    const int ac = (tid & 3) * 16;     // A-staging col group (16 f32 = 64B contiguous)
    const int wbase = (wc * 64 + l15) * 32 + g8;   // W-fragment base (shorts) within a K=32 chunk

    // 2-deep register prefetch slots (statically indexed — full unroll)
    float4 vaA[2][4];                  // A: this thread's 16 f32
    s16x8  wW[2][8];                   // W: 8 fragments = 2 kk x 4 j (16B each, L2)

#define G1_ISSUE(KC2, S) do { \
        const float* _src = &net_in[(row0 + ar) * 512 + (KC2) * 64 + ac]; \
        vaA[S][0] = *(const float4*)(_src); \
        vaA[S][1] = *(const float4*)(_src + 4); \
        vaA[S][2] = *(const float4*)(_src + 8); \
        vaA[S][3] = *(const float4*)(_src + 12); \
        const unsigned short* _wp = W1T + (KC2) * 16384 + wbase; \
        wW[S][0] = *(const s16x8*)(_wp); \
        wW[S][1] = *(const s16x8*)(_wp + 512); \
        wW[S][2] = *(const s16x8*)(_wp + 1024); \
        wW[S][3] = *(const s16x8*)(_wp + 1536); \
        wW[S][4] = *(const s16x8*)(_wp + 8192); \
        wW[S][5] = *(const s16x8*)(_wp + 8704); \
        wW[S][6] = *(const s16x8*)(_wp + 9216); \
        wW[S][7] = *(const s16x8*)(_wp + 9728); \
    } while (0)

#define G1_WRITE(KC2, S) do { \
        int4 _p0, _p1; \
        asm("v_cvt_pk_bf16_f32 %0, %1, %2" : "=v"(_p0.x) : "v"(vaA[S][0].x), "v"(vaA[S][0].y)); \
        asm("v_cvt_pk_bf16_f32 %0, %1, %2" : "=v"(_p0.y) : "v"(vaA[S][0].z), "v"(vaA[S][0].w)); \
        asm("v_cvt_pk_bf16_f32 %0, %1, %2" : "=v"(_p0.z) : "v"(vaA[S][1].x), "v"(vaA[S][1].y)); \
        asm("v_cvt_pk_bf16_f32 %0, %1, %2" : "=v"(_p0.w) : "v"(vaA[S][1].z), "v"(vaA[S][1].w)); \
        asm("v_cvt_pk_bf16_f32 %0, %1, %2" : "=v"(_p1.x) : "v"(vaA[S][2].x), "v"(vaA[S][2].y)); \
        asm("v_cvt_pk_bf16_f32 %0, %1, %2" : "=v"(_p1.y) : "v"(vaA[S][2].z), "v"(vaA[S][2].w)); \
        asm("v_cvt_pk_bf16_f32 %0, %1, %2" : "=v"(_p1.z) : "v"(vaA[S][3].x), "v"(vaA[S][3].y)); \
        asm("v_cvt_pk_bf16_f32 %0, %1, %2" : "=v"(_p1.w) : "v"(vaA[S][3].z), "v"(vaA[S][3].w)); \
        unsigned short* _d = &Abuf[(KC2) & 1][ar][ac]; \
        *(int4*)(_d) = _p0; \
        *(int4*)(_d + 8) = _p1; \
    } while (0)

    // prologue: chunks 0 and 1 in flight; chunk 0's A written
    G1_ISSUE(0, 0);
    G1_ISSUE(1, 1);
    G1_WRITE(0, 0);
    wg_barrier_lds();

    #pragma unroll
    for (int kc2 = 0; kc2 < 8; ++kc2) {
        const int cur = kc2 & 1;
        // consume current W slot into locals BEFORE reissuing it (SSA hygiene)
        s16x8 b0 = wW[cur][0], b1r = wW[cur][1], b2 = wW[cur][2], b3 = wW[cur][3];
        s16x8 b4 = wW[cur][4], b5 = wW[cur][5], b6 = wW[cur][6], b7 = wW[cur][7];
        // issue chunk kc2+2 into the slot just freed
        if (kc2 < 6) G1_ISSUE(kc2 + 2, cur);
        // write chunk kc2+1's A (loads issued at kc2-1 -> a full iteration of cover)
        if (kc2 < 7) G1_WRITE(kc2 + 1, (kc2 + 1) & 1);
        // kk = 0 sub-chunk
        {
            s16x8 af[4];
            #pragma unroll
            for (int i = 0; i < 4; ++i)
                af[i] = *(const s16x8*)&Abuf[cur][wr * 64 + i * 16 + l15][g8];
            #pragma unroll
            for (int i = 0; i < 4; ++i) {
                acc[i][0] = __builtin_amdgcn_mfma_f32_16x16x32_bf16(af[i], b0, acc[i][0], 0, 0, 0);
                acc[i][1] = __builtin_amdgcn_mfma_f32_16x16x32_bf16(af[i], b1r, acc[i][1], 0, 0, 0);
                acc[i][2] = __builtin_amdgcn_mfma_f32_16x16x32_bf16(af[i], b2, acc[i][2], 0, 0, 0);
                acc[i][3] = __builtin_amdgcn_mfma_f32_16x16x32_bf16(af[i], b3, acc[i][3], 0, 0, 0);
            }
        }
        // kk = 1 sub-chunk
        {
            s16x8 af[4];
            #pragma unroll
            for (int i = 0; i < 4; ++i)
                af[i] = *(const s16x8*)&Abuf[cur][wr * 64 + i * 16 + l15][32 + g8];
            #pragma unroll
            for (int i = 0; i < 4; ++i) {
                acc[i][0] = __builtin_amdgcn_mfma_f32_16x16x32_bf16(af[i], b4, acc[i][0], 0, 0, 0);
                acc[i][1] = __builtin_amdgcn_mfma_f32_16x16x32_bf16(af[i], b5, acc[i][1], 0, 0, 0);
                acc[i][2] = __builtin_amdgcn_mfma_f32_16x16x32_bf16(af[i], b6, acc[i][2], 0, 0, 0);
                acc[i][3] = __builtin_amdgcn_mfma_f32_16x16x32_bf16(af[i], b7, acc[i][3], 0, 0, 0);
            }
        }
        wg_barrier_lds();
    }
#undef G1_ISSUE
#undef G1_WRITE

    // epilogue: H = relu(acc + b1) -> Hbuf.  D layout: col=lane&15, row=(lane>>4)*4+r
    #pragma unroll
    for (int j = 0; j < 4; ++j) {
        int col = wc * 64 + j * 16 + l15;
        float bb = b1[col];
        #pragma unroll
        for (int i = 0; i < 4; ++i) {
            #pragma unroll
            for (int r = 0; r < 4; ++r) {
                int row = (wr * 4 + i) * 16 + (lane >> 4) * 4 + r;
                Hbuf[row][col] = f2bf(fmaxf(acc[i][j][r] + bb, 0.f));
            }
        }
    }
    __syncthreads();   // Hbuf visible to all waves

    // ========== link column: lc_k = h_k . Wf[:,256]  (wave wid owns position wid) ==========
    float wl0 = Wf[(lane * 4 + 0) * 257 + 256];
    float wl1 = Wf[(lane * 4 + 1) * 257 + 256];
    float wl2 = Wf[(lane * 4 + 2) * 257 + 256];
    float wl3 = Wf[(lane * 4 + 3) * 257 + 256];
    float bf256 = bfv[256];

    float lcreg = 0.f;
    for (int k = 0; k < 16; ++k) {
        ushort4 hv = *(const ushort4*)&Hbuf[wid * 16 + k][lane * 4];
        float p = bf2f(hv.x) * wl0 + bf2f(hv.y) * wl1 + bf2f(hv.z) * wl2 + bf2f(hv.w) * wl3;
        #pragma unroll
        for (int off = 32; off > 0; off >>= 1) p += __shfl_xor(p, off, 64);
        if (lane == k) lcreg = p;
    }

    // ========== weights: w_k, ww_k = w_k*m_k, s, updates_256 ==========
    float wwreg = 0.f;
    float u256 = 0.f;
    if (lane < 16) {
        float mv  = mg[(blk * 8 + wid) * 16 + lane];
        float raw = lcreg + bf256;
        float sg  = 1.f / (1.f + expf(-raw));
        float v   = mv * sg;
        float lw  = v + 1e-8f;
        float nrm = lw;
        #pragma unroll
        for (int off = 8; off > 0; off >>= 1) nrm += __shfl_xor(nrm, off, 16);
        float wk = lw / nrm;
        wwreg = wk * mv;
        float u = wk * v;
        float s = wwreg;
        #pragma unroll
        for (int off = 8; off > 0; off >>= 1) {
            u += __shfl_xor(u, off, 16);
            s += __shfl_xor(s, off, 16);
        }
        u256 = u;
        if (lane == 0) sbuf[wid] = s;
    }
    u256 = __shfl(u256, 0, 64);   // broadcast to all 64 lanes of this wave

    // ========== g_p = sum_k ww_k * h_k  -> gbuf (bf16), rows 8..15 zero ==========
    {
        float ga0 = 0.f, ga1 = 0.f, ga2 = 0.f, ga3 = 0.f;
        #pragma unroll
        for (int k = 0; k < 16; ++k) {
            float wwk = __shfl(wwreg, k, 64);
            ushort4 hv = *(const ushort4*)&Hbuf[wid * 16 + k][lane * 4];
            ga0 += wwk * bf2f(hv.x);
            ga1 += wwk * bf2f(hv.y);
            ga2 += wwk * bf2f(hv.z);
            ga3 += wwk * bf2f(hv.w);
        }
        ushort4 gw; gw.x = f2bf(ga0); gw.y = f2bf(ga1); gw.z = f2bf(ga2); gw.w = f2bf(ga3);
        *(ushort4*)&gbuf[wid][lane * 4] = gw;
        ushort4 z4; z4.x = 0; z4.y = 0; z4.z = 0; z4.w = 0;
        *(ushort4*)&gbuf[8 + wid][lane * 4] = z4;
    }
    __syncthreads();   // gbuf ready

    // ========== GEMM2': updates[:, :256] = g @ Wf[:, :256] — B from L2, ZERO barriers ==========
    f32x4 acc2[2];
    acc2[0] = zero4; acc2[1] = zero4;
    {
        const int w2n0 = ((wid * 2 + 0) * 16 + l15) * 32 + g8;
        const int w2n1 = ((wid * 2 + 1) * 16 + l15) * 32 + g8;
        s16x8 w2a[2], w2b[2];
        w2a[0] = *(const s16x8*)(WfT + w2n0);
        w2b[0] = *(const s16x8*)(WfT + w2n1);
        #pragma unroll
        for (int c2 = 0; c2 < 8; ++c2) {
            const int cur = c2 & 1;
            s16x8 ba = w2a[cur], bb = w2b[cur];
            if (c2 < 7) {
                w2a[cur ^ 1] = *(const s16x8*)(WfT + (c2 + 1) * 8192 + w2n0);
                w2b[cur ^ 1] = *(const s16x8*)(WfT + (c2 + 1) * 8192 + w2n1);
            }
            s16x8 ga = *(const s16x8*)&gbuf[l15][c2 * 32 + g8];
            acc2[0] = __builtin_amdgcn_mfma_f32_16x16x32_bf16(ga, ba, acc2[0], 0, 0, 0);
            acc2[1] = __builtin_amdgcn_mfma_f32_16x16x32_bf16(ga, bb, acc2[1], 0, 0, 0);
        }
    }

    // updates -> LDS (rows 0..7 valid)
    {
        int gq = lane >> 4;   // 0..3 ; D rows gq*4+r, only rows 0..7 are positions
        if (gq < 2) {
            #pragma unroll
            for (int t = 0; t < 2; ++t) {
                int col = (wid * 2 + t) * 16 + l15;
                float bfc = bfv[col];
                #pragma unroll
                for (int r = 0; r < 4; ++r) {
                    int p = gq * 4 + r;
                    updb[p][col] = acc2[t][r] + sbuf[p] * bfc;
                }
            }
        }
    }
    __syncthreads();

    // ========== embeds update + LayerNorm (wave wid owns position wid) ==========
    {
        int base = (blk * 8 + wid) * 256;
        float4 up = *(const float4*)&updb[wid][lane * 4];
        float4 em = *(const float4*)&embeds[base + lane * 4];
        float e0 = em.x + u256 * up.x;
        float e1 = em.y + u256 * up.y;
        float e2 = em.z + u256 * up.z;
        float e3 = em.w + u256 * up.w;
        float s1 = e0 + e1 + e2 + e3;
        float s2 = e0 * e0 + e1 * e1 + e2 * e2 + e3 * e3;
        #pragma unroll
        for (int off = 32; off > 0; off >>= 1) {
            s1 += __shfl_xor(s1, off, 64);
            s2 += __shfl_xor(s2, off, 64);
        }
        float mu  = s1 * (1.f / 256.f);
        float var = s2 * (1.f / 256.f) - mu * mu;
        float rs  = rsqrtf(var + 1e-5f);
        float4 gm = *(const float4*)&gam[lane * 4];
        float4 bt = *(const float4*)&bet[lane * 4];
        float4 o;
        o.x = (e0 - mu) * rs * gm.x + bt.x;
        o.y = (e1 - mu) * rs * gm.y + bt.y;
        o.z = (e2 - mu) * rs * gm.z + bt.z;
        o.w = (e3 - mu) * rs * gm.w + bt.w;
        *(float4*)&out[base + lane * 4] = o;
    }
}

extern "C" void kernel_launch(void* const* d_in, const int* in_sizes, int n_in,
                              void* d_out, int out_size, void* d_ws, size_t ws_size,
                              hipStream_t stream) {
    (void)in_sizes; (void)n_in; (void)ws_size; (void)out_size;
    const float* net_in = (const float*)d_in[0];
    const float* embeds = (const float*)d_in[1];
    const float* mg     = (const float*)d_in[2];
    const float* W1     = (const float*)d_in[3];
    const float* b1     = (const float*)d_in[4];
    const float* Wf     = (const float*)d_in[5];
    const float* bfv    = (const float*)d_in[6];
    const float* gam    = (const float*)d_in[7];
    const float* bet    = (const float*)d_in[8];
    float* outp = (float*)d_out;

    unsigned short* W1T = (unsigned short*)d_ws;                 // 16*256*32 = 131072 elems
    unsigned short* WfT = W1T + 131072;                          //  8*256*32 =  65536 elems

    prep_weights<<<512, 256, 0, stream>>>(W1, Wf, W1T, WfT);
    fused_embed<<<NBLK, 512, 0, stream>>>(net_in, embeds, mg, W1, b1, Wf, bfv, gam, bet, outp, W1T, WfT);
}